// Round 1
// baseline (49.379 us; speedup 1.0000x reference)
//
#include <hip/hip_runtime.h>

// SymbolicTraversal: out[b, n] = max(0, max_{e: type[e]==r_index[b], dst[e]==n} h[b, src[e]])
// Strategy: single pass over edges; per-block shared table mapping relation -> batch bitmask;
// integer atomicMax with float-as-int trick (all committed values > 0).

#define TBL 128

__global__ void traverse_kernel(const float* __restrict__ h,
                                const int* __restrict__ edge_index, // [2][E]
                                const int* __restrict__ etype,      // [E]
                                const int* __restrict__ r_index,    // [B]
                                int* __restrict__ out,              // [B][N] as int bits
                                int B, int N, int E) {
    __shared__ unsigned int smask[TBL];
    for (int r = threadIdx.x; r < TBL; r += blockDim.x) {
        unsigned int m = 0;
        for (int b = 0; b < B; ++b)
            if (r_index[b] == r) m |= (1u << b);
        smask[r] = m;
    }
    __syncthreads();

    const int* __restrict__ src = edge_index;
    const int* __restrict__ dst = edge_index + E;

    int tid = blockIdx.x * blockDim.x + threadIdx.x;
    int e4 = tid * 4;

    if (e4 + 3 < E) {
        int4 t = *reinterpret_cast<const int4*>(etype + e4);
        int types[4] = {t.x, t.y, t.z, t.w};
        unsigned int masks[4];
        bool any = false;
        #pragma unroll
        for (int i = 0; i < 4; ++i) {
            unsigned int tt = (unsigned int)types[i];
            masks[i] = (tt < TBL) ? smask[tt] : 0u;
            any = any || (masks[i] != 0u);
        }
        if (!any) return;
        int4 s4 = *reinterpret_cast<const int4*>(src + e4);
        int4 d4 = *reinterpret_cast<const int4*>(dst + e4);
        int ss[4] = {s4.x, s4.y, s4.z, s4.w};
        int dd[4] = {d4.x, d4.y, d4.z, d4.w};
        #pragma unroll
        for (int i = 0; i < 4; ++i) {
            unsigned int m = masks[i];
            while (m) {
                int b = __builtin_ctz(m);
                m &= m - 1;
                float v = h[(size_t)b * N + ss[i]];
                if (v > 0.0f)
                    atomicMax(out + (size_t)b * N + dd[i], __float_as_int(v));
            }
        }
    } else if (e4 < E) {
        for (int e = e4; e < E; ++e) {
            unsigned int tt = (unsigned int)etype[e];
            unsigned int m = (tt < TBL) ? smask[tt] : 0u;
            while (m) {
                int b = __builtin_ctz(m);
                m &= m - 1;
                float v = h[(size_t)b * N + src[e]];
                if (v > 0.0f)
                    atomicMax(out + (size_t)b * N + dst[e], __float_as_int(v));
            }
        }
    }
}

extern "C" void kernel_launch(void* const* d_in, const int* in_sizes, int n_in,
                              void* d_out, int out_size, void* d_ws, size_t ws_size,
                              hipStream_t stream) {
    const float* h          = (const float*)d_in[0];
    const int*   edge_index = (const int*)d_in[1];
    const int*   etype      = (const int*)d_in[2];
    const int*   r_index    = (const int*)d_in[3];

    const int B = in_sizes[3];
    const int N = in_sizes[0] / B;
    const int E = in_sizes[2];

    // out = 0.0f everywhere (handles empty segments + clamp(min=0) floor)
    hipMemsetAsync(d_out, 0, (size_t)out_size * sizeof(float), stream);

    const int threads = 256;
    const int nquads  = (E + 3) / 4;
    const int blocks  = (nquads + threads - 1) / threads;

    traverse_kernel<<<blocks, threads, 0, stream>>>(
        h, edge_index, etype, r_index, (int*)d_out, B, N, E);
}